// Round 9
// baseline (315.898 us; speedup 1.0000x reference)
//
#include <hip/hip_runtime.h>

typedef __attribute__((ext_vector_type(8))) short short8;
typedef __attribute__((ext_vector_type(4))) float f32x4;
typedef __attribute__((ext_vector_type(4))) unsigned short u16x4;
typedef __attribute__((ext_vector_type(2))) unsigned int u32x2;
typedef __attribute__((ext_vector_type(4))) unsigned int u32x4;

__device__ __forceinline__ float bf2f(unsigned short u) {
    return __uint_as_float(((unsigned)u) << 16);
}
__device__ __forceinline__ unsigned short f2bf(float f) {
    unsigned u = __float_as_uint(f);
    u += 0x7fffu + ((u >> 16) & 1u);   // round-to-nearest-even
    return (unsigned short)(u >> 16);
}
// HW packed f32->bf16 convert (RNE): lo16=cvt(a), hi16=cvt(b).
__device__ __forceinline__ unsigned pack2(float a, float b) {
    unsigned r;
    asm("v_cvt_pk_bf16_f32 %0, %1, %2" : "=v"(r) : "v"(a), "v"(b));
    return r;
}
__device__ __forceinline__ void load_lds16(const void* g, void* l) {
    __builtin_amdgcn_global_load_lds(
        (const __attribute__((address_space(1))) void*)g,
        (__attribute__((address_space(3))) void*)l, 16, 0, 0);
}
// device-side dtype probe (only used by cast_all, which runs fp32-only now)
__device__ __forceinline__ bool is_bf16(const unsigned* dt) {
    return *dt == 0x3F803F80u;
}
// gelu via exact identity 0.5*(1+tanh(u)) = sigmoid(2u); overflow-safe.
__device__ __forceinline__ float gelu_fast(float t) {
    float q = t * (1.5957691f + 0.07135482f * t * t);   // 2u
    float e = __expf(-q);
    return __fdividef(t, 1.0f + e);
}

// ---------------------------------------------------------------------------
// One-shot cast of all weights/params to bf16 in ws (fp32 datasets only).
// ---------------------------------------------------------------------------
__global__ __launch_bounds__(512) void cast_all(
    const void* s_wqkv, const void* s_wproj, const void* s_w1, const void* s_w2,
    const void* v0, const void* v1, const void* v2, const void* v3,
    const void* v4, const void* v5, const void* v6,
    unsigned short* d_wqkv, unsigned short* d_wproj, unsigned short* d_w1,
    unsigned short* d_w2, unsigned short* par, const unsigned* dt)
{
    bool isbf = is_bf16(dt);
    int b = blockIdx.x, tid = threadIdx.x;
    if (b < 768) {
        const void* src; unsigned short* dst; int off;
        if (b < 192)      { src = s_wqkv;  dst = d_wqkv;  off = b * 4096; }
        else if (b < 256) { src = s_wproj; dst = d_wproj; off = (b - 192) * 4096; }
        else if (b < 512) { src = s_w1;    dst = d_w1;    off = (b - 256) * 4096; }
        else              { src = s_w2;    dst = d_w2;    off = (b - 512) * 4096; }
        int i = off + tid * 8;
        if (isbf) {
            *(short8*)(dst + i) = *(const short8*)((const unsigned short*)src + i);
        } else {
            const float* s = (const float*)src + i;
            short8 o;
            #pragma unroll
            for (int j = 0; j < 8; ++j) o[j] = (short)f2bf(s[j]);
            *(short8*)(dst + i) = o;
        }
    } else {
        const void* srcs[7]  = {v0, v1, v2, v3, v4, v5, v6};
        const int   sizes[7] = {512, 512, 512, 512, 512, 2048, 512};
        const int   offs[7]  = {0, 512, 1024, 1536, 2048, 2560, 4608};
        int j = b - 768;
        const void* s = srcs[j];
        unsigned short* d = par + offs[j];
        for (int i = tid; i < sizes[j]; i += 512)
            d[i] = isbf ? ((const unsigned short*)s)[i] : f2bf(((const float*)s)[i]);
    }
}

// ---------------------------------------------------------------------------
// LayerNorm: one wave per row of 512, lane owns 8 contiguous elements.
// ---------------------------------------------------------------------------
__global__ __launch_bounds__(256) void ln_kernel(
    const void* __restrict__ xin, size_t row0, int isf32,
    const unsigned short* __restrict__ g, const unsigned short* __restrict__ b,
    unsigned short* __restrict__ y)
{
    int w = threadIdx.x >> 6, lane = threadIdx.x & 63;
    size_t lr = (size_t)blockIdx.x * 4 + w;
    size_t gr = row0 + lr;
    float v[8];
    if (isf32) {
        const float* xr = (const float*)xin + (gr << 9) + (lane << 3);
        #pragma unroll
        for (int j = 0; j < 8; ++j) v[j] = xr[j];
    } else {
        short8 raw = *(const short8*)((const unsigned short*)xin + (gr << 9) + (lane << 3));
        #pragma unroll
        for (int j = 0; j < 8; ++j) v[j] = bf2f((unsigned short)raw[j]);
    }
    float sum = 0.f, sq = 0.f;
    #pragma unroll
    for (int j = 0; j < 8; ++j) { sum += v[j]; sq += v[j] * v[j]; }
    #pragma unroll
    for (int off = 32; off > 0; off >>= 1) {
        sum += __shfl_xor(sum, off);
        sq  += __shfl_xor(sq, off);
    }
    float mu  = sum * (1.0f / 512.0f);
    float var = sq * (1.0f / 512.0f) - mu * mu;
    float rs  = rsqrtf(var + 1e-5f);
    short8 gr8 = *(const short8*)(g + (lane << 3));
    short8 br8 = *(const short8*)(b + (lane << 3));
    float o[8];
    #pragma unroll
    for (int j = 0; j < 8; ++j)
        o[j] = (v[j] - mu) * rs * bf2f((unsigned short)gr8[j]) + bf2f((unsigned short)br8[j]);
    u32x4 ov = {pack2(o[0], o[1]), pack2(o[2], o[3]),
                pack2(o[4], o[5]), pack2(o[6], o[7])};
    *(u32x4*)(y + (lr << 9) + (lane << 3)) = ov;
}

// ---------------------------------------------------------------------------
// gemm_256 (R9): 256x256 tile, BK=64, 512 thr / 8 waves (2M x 4N), wave
// tile 128x64, acc[4][8].  Double-buffered LDS 128KB (per buf: A 256x128B
// @0, B 256x128B @32768), 1 block/CU, __launch_bounds__(512,2) = 256-reg
// budget (est ~230 incl. 128 acc).
// Per K-tile: 4 quadrant phases.  Phase q: {B-frags read once at q=0 (8 x
// ds_read_b128, held in regs), A-quadrant reads (4), 2-3 global_load_lds
// of tile T+1 into buf^1 (8 spread as 3/3/2/0 -> last issue has >=2 phases
// of MFMA cover over HBM latency), s_barrier, lgkmcnt(0)+sched_barrier,
// setprio(1), 16 MFMA, setprio(0), s_barrier}.  Boundary: vmcnt(0) before
// q=3's closing barrier (T+1's loads issued ~3 phases earlier -> drain
// nearly free; this kills the uncovered stage->drain stall that capped
// gemm_big at 23% MfmaUtil).
// Addressing algebra identical to the session-verified scheme: slot(row,c)
// holds global chunk c^(row&7); staging slot byte = tid*16 (srow=tid>>3 in
// [0,64), 4 row-groups of 64 per operand); frag chunk = ((4s+g)^(l15&7))<<4;
// MFMA operand-swapped (A=W frag).  Epilogue: bias+gelu in-register (mode
// 2), two-half 128-row transpose through LDS (512B rows, sw=mloc&62,
// readout c16 = lc ^ ((row>>1)&31)), coalesced 16B stores.
// Use only where grid = (N/256)*(M/256) is a multiple of 256 (mlp1: 512).
// ---------------------------------------------------------------------------
__global__ __launch_bounds__(512, 2) void gemm_256(
    const unsigned short* __restrict__ A, const unsigned short* __restrict__ W,
    const unsigned short* __restrict__ bias,
    unsigned short* __restrict__ out,
    int NBY, int N, int K, int mode)
{
    __shared__ char lds[131072];

    int tid = threadIdx.x;
    int w = tid >> 6, lane = tid & 63;
    int l15 = lane & 15, g = lane >> 4;

    int L = blockIdx.x;
    int bx, by;
    if ((NBY & 7) == 0) {
        int nby8 = NBY >> 3;
        int xcd = L & 7, i = L >> 3;
        by = xcd * nby8 + (i % nby8);
        bx = i / nby8;
    } else {
        by = L % NBY;
        bx = L / NBY;
    }
    int m0 = by << 8, n0 = bx << 8;
    int wm = (w >> 2) << 7;                  // 0,128
    int wn = (w & 3) << 6;                   // 0,64,128,192

    int srow = tid >> 3;                     // [0,64)
    int u = (tid & 7) ^ (srow & 7);
    const unsigned short* gA[4];
    const unsigned short* gB[4];
    #pragma unroll
    for (int j = 0; j < 4; ++j) {
        gA[j] = A + (size_t)(m0 + j * 64 + srow) * K + u * 8;
        gB[j] = W + (size_t)(n0 + j * 64 + srow) * K + u * 8;
    }
    int lslot = tid * 16;                    // [0,8192)
    int swz = l15 & 7;

    f32x4 acc[4][8];                         // [n-frag i][m-frag j]
    #pragma unroll
    for (int i = 0; i < 4; ++i)
        #pragma unroll
        for (int j = 0; j < 8; ++j) acc[i][j] = (f32x4){0.f, 0.f, 0.f, 0.f};

    // prologue: stage tile 0 into buf 0
    #pragma unroll
    for (int j = 0; j < 4; ++j) {
        load_lds16(gA[j], &lds[j * 8192 + lslot]);
        load_lds16(gB[j], &lds[32768 + j * 8192 + lslot]);
    }
    asm volatile("s_waitcnt vmcnt(0)" ::: "memory");
    __builtin_amdgcn_s_barrier();
    __builtin_amdgcn_sched_barrier(0);

    int nk = K >> 6;
    int p = 0;
    for (int T = 0; T < nk; ++T) {
        const char* bA = &lds[p * 65536];
        const char* bW = bA + 32768;
        char* nb = &lds[(p ^ 1) * 65536];
        bool hn = (T + 1 < nk);
        int kn = (T + 1) << 6;

        short8 bf[4][2];                     // B-frags, whole K-tile, in regs
        #pragma unroll
        for (int q = 0; q < 4; ++q) {
            // ds-reads for this phase
            if (q == 0) {
                #pragma unroll
                for (int s = 0; s < 2; ++s) {
                    int cs = ((s * 4 + g) ^ swz) << 4;
                    #pragma unroll
                    for (int i = 0; i < 4; ++i)
                        bf[i][s] = *(const short8*)(bW + (wn + i * 16 + l15) * 128 + cs);
                }
            }
            short8 af[2][2];
            #pragma unroll
            for (int s = 0; s < 2; ++s) {
                int cs = ((s * 4 + g) ^ swz) << 4;
                #pragma unroll
                for (int jj = 0; jj < 2; ++jj)
                    af[jj][s] = *(const short8*)(bA + (wm + (2 * q + jj) * 16 + l15) * 128 + cs);
            }
            // stage tile T+1 (8 loads spread 3/3/2/0)
            if (hn) {
                if (q == 0) {
                    load_lds16(gA[0] + kn, nb + lslot);
                    load_lds16(gA[1] + kn, nb + 8192 + lslot);
                    load_lds16(gA[2] + kn, nb + 16384 + lslot);
                } else if (q == 1) {
                    load_lds16(gA[3] + kn, nb + 24576 + lslot);
                    load_lds16(gB[0] + kn, nb + 32768 + lslot);
                    load_lds16(gB[1] + kn, nb + 40960 + lslot);
                } else if (q == 2) {
                    load_lds16(gB[2] + kn, nb + 49152 + lslot);
                    load_lds16(gB[3] + kn, nb + 57344 + lslot);
                }
            }
            __builtin_amdgcn_s_barrier();
            asm volatile("s_waitcnt lgkmcnt(0)" ::: "memory");
            __builtin_amdgcn_sched_barrier(0);
            __builtin_amdgcn_s_setprio(1);
            #pragma unroll
            for (int s = 0; s < 2; ++s)
                #pragma unroll
                for (int jj = 0; jj < 2; ++jj)
                    #pragma unroll
                    for (int i = 0; i < 4; ++i)
                        acc[i][2 * q + jj] = __builtin_amdgcn_mfma_f32_16x16x32_bf16(
                            bf[i][s], af[jj][s], acc[i][2 * q + jj], 0, 0, 0);
            __builtin_amdgcn_s_setprio(0);
            if (q == 3 && hn)
                asm volatile("s_waitcnt vmcnt(0)" ::: "memory");
            __builtin_amdgcn_s_barrier();
            __builtin_amdgcn_sched_barrier(0);
        }
        p ^= 1;
    }
    // after the last closing barrier all LDS reads are done -> LDS free.

    if (mode == 2) {
        #pragma unroll
        for (int i = 0; i < 4; ++i) {
            u16x4 bb = *(const u16x4*)(bias + n0 + wn + i * 16 + g * 4);
            #pragma unroll
            for (int j = 0; j < 8; ++j)
                #pragma unroll
                for (int r = 0; r < 4; ++r)
                    acc[i][j][r] = gelu_fast(acc[i][j][r] + bf2f(bb[r]));
        }
    }

    // two-half transpose + readout (128 rows x 512B per half)
    #pragma unroll
    for (int hh = 0; hh < 2; ++hh) {
        if ((w >> 2) == hh) {
            #pragma unroll
            for (int j = 0; j < 8; ++j) {
                int mloc = j * 16 + l15;
                char* rowp = (char*)lds + mloc * 512;
                int sw = mloc & 62;
                #pragma unroll
                for (int i = 0; i < 4; ++i) {
                    int cq = (wn + i * 16 + g * 4) >> 2;
                    u32x2 pk = {pack2(acc[i][j][0], acc[i][j][1]),
                                pack2(acc[i][j][2], acc[i][j][3])};
                    *(u32x2*)(rowp + ((cq ^ sw) << 3)) = pk;
                }
            }
        }
        __syncthreads();
        int rL = tid >> 5, lc = tid & 31;
        int colg = n0 + lc * 8;
        #pragma unroll
        for (int ps = 0; ps < 8; ++ps) {
            int row = ps * 16 + rL;
            int rowL = m0 + hh * 128 + row;
            int c16 = lc ^ ((row >> 1) & 31);
            short8 vv = *(const short8*)((char*)lds + row * 512 + (c16 << 4));
            *(short8*)(out + (size_t)rowL * N + colg) = vv;
        }
        if (hh == 0) __syncthreads();
    }
}

// ---------------------------------------------------------------------------
// gemm8: BM=BN=128, BK=64, 256 thr, single 32KB buffer, 2-barrier loop,
// ~3 blocks/CU.  Used for qkv (mode 0), proj (mode 1), mlp2 (mode 3).
// ---------------------------------------------------------------------------
__global__ __launch_bounds__(256) void gemm8(
    const unsigned short* __restrict__ A, const unsigned short* __restrict__ W,
    const unsigned short* __restrict__ bias,
    const void* __restrict__ resid, size_t rrow0,
    void* __restrict__ out, size_t orow0,
    int NBY, int N, int K, int mode, int inbf)
{
    constexpr int BN = 128;
    __shared__ char lds[32768];

    int tid = threadIdx.x;
    int w = tid >> 6, lane = tid & 63;
    int l15 = lane & 15, g = lane >> 4;

    int L = blockIdx.x;
    int bx, by;
    if ((NBY & 7) == 0) {
        int nby8 = NBY >> 3;
        int xcd = L & 7, i = L >> 3;
        by = xcd * nby8 + (i % nby8);
        bx = i / nby8;
    } else {
        by = L % NBY;
        bx = L / NBY;
    }
    int m0 = by << 7, n0 = bx << 7;
    int wm = (w >> 1) << 6;
    int wn = (w & 1) << 6;

    int srow_t = tid >> 3;
    int u_t = (tid & 7) ^ (srow_t & 7);
    const unsigned short* gA[4];
    const unsigned short* gB[4];
    #pragma unroll
    for (int j = 0; j < 4; ++j) {
        gA[j] = A + (size_t)(m0 + j * 32 + srow_t) * K + u_t * 8;
        gB[j] = W + (size_t)(n0 + j * 32 + srow_t) * K + u_t * 8;
    }
    int lslot = tid * 16;
    int swz = l15 & 7;

    f32x4 acc[4][4];
    #pragma unroll
    for (int i = 0; i < 4; ++i)
        #pragma unroll
        for (int j = 0; j < 4; ++j) acc[i][j] = (f32x4){0.f, 0.f, 0.f, 0.f};

    for (int k = 0; k < K; k += 64) {
        if (k > 0) __syncthreads();
        #pragma unroll
        for (int j = 0; j < 4; ++j) {
            load_lds16(gA[j] + k, &lds[j * 4096 + lslot]);
            load_lds16(gB[j] + k, &lds[16384 + j * 4096 + lslot]);
        }
        __syncthreads();
        const char* bAct = lds;
        const char* bW = bAct + 16384;
        #pragma unroll
        for (int s = 0; s < 2; ++s) {
            int cs = ((s * 4 + g) ^ swz) << 4;
            short8 wf[4], af[4];
            #pragma unroll
            for (int i = 0; i < 4; ++i)
                wf[i] = *(const short8*)(bW + (wn + i * 16 + l15) * 128 + cs);
            #pragma unroll
            for (int j = 0; j < 4; ++j)
                af[j] = *(const short8*)(bAct + (wm + j * 16 + l15) * 128 + cs);
            #pragma unroll
            for (int i = 0; i < 4; ++i)
                #pragma unroll
                for (int j = 0; j < 4; ++j)
                    acc[i][j] = __builtin_amdgcn_mfma_f32_16x16x32_bf16(wf[i], af[j], acc[i][j], 0, 0, 0);
        }
    }
    __syncthreads();

    char* tb = (char*)lds;
    #pragma unroll
    for (int j = 0; j < 4; ++j) {
        int mloc = wm + j * 16 + l15;
        char* rowp = tb + mloc * (BN * 2);
        int sw = mloc & (BN / 4 - 2);
        #pragma unroll
        for (int i = 0; i < 4; ++i) {
            int cq = (wn + i * 16 + g * 4) >> 2;
            u32x2 pk = {pack2(acc[i][j][0], acc[i][j][1]),
                        pack2(acc[i][j][2], acc[i][j][3])};
            *(u32x2*)(rowp + ((cq ^ sw) << 3)) = pk;
        }
    }
    __syncthreads();

    int rL = tid >> 4;
    int lc = tid & 15;
    int colg = n0 + lc * 8;
    float bv[8];
    if (mode != 0) {
        short8 bb = *(const short8*)(bias + colg);
        #pragma unroll
        for (int t = 0; t < 8; ++t) bv[t] = bf2f((unsigned short)bb[t]);
    }

    #pragma unroll
    for (int ps = 0; ps < 8; ++ps) {
        int row = ps * 16 + rL;
        int rowL = m0 + row;
        int c16 = lc ^ ((row >> 1) & 15);
        short8 vv = *(const short8*)(tb + row * (BN * 2) + (c16 << 4));

        if (mode == 0) {
            *(short8*)((unsigned short*)out + (size_t)rowL * N + colg) = vv;
        } else if (mode == 1) {
            size_t rbase = (rrow0 + rowL) * (size_t)N + colg;
            float o8[8];
            if (inbf) {
                short8 rr = *(const short8*)((const unsigned short*)resid + rbase);
                #pragma unroll
                for (int t = 0; t < 8; ++t)
                    o8[t] = bf2f((unsigned short)rr[t]) + bf2f((unsigned short)vv[t]) + bv[t];
            } else {
                f32x4 r0 = *(const f32x4*)((const float*)resid + rbase);
                f32x4 r1 = *(const f32x4*)((const float*)resid + rbase + 4);
                #pragma unroll
                for (int t = 0; t < 4; ++t) {
                    o8[t]     = r0[t] + bf2f((unsigned short)vv[t]) + bv[t];
                    o8[t + 4] = r1[t] + bf2f((unsigned short)vv[t + 4]) + bv[t + 4];
                }
            }
            u32x4 ov = {pack2(o8[0], o8[1]), pack2(o8[2], o8[3]),
                        pack2(o8[4], o8[5]), pack2(o8[6], o8[7])};
            *(u32x4*)((unsigned short*)out + (size_t)rowL * N + colg) = ov;
        } else {
            size_t rbase = (size_t)rowL * N + colg;
            short8 rr = *(const short8*)((const unsigned short*)resid + rbase);
            float o8[8];
            #pragma unroll
            for (int t = 0; t < 8; ++t)
                o8[t] = bf2f((unsigned short)rr[t]) + bf2f((unsigned short)vv[t]) + bv[t];
            size_t obase = (orow0 + rowL) * (size_t)N + colg;
            if (inbf) {
                u32x4 ov = {pack2(o8[0], o8[1]), pack2(o8[2], o8[3]),
                            pack2(o8[4], o8[5]), pack2(o8[6], o8[7])};
                *(u32x4*)((unsigned short*)out + obase) = ov;
            } else {
                float* ob = (float*)out + obase;
                *(f32x4*)ob       = (f32x4){o8[0], o8[1], o8[2], o8[3]};
                *(f32x4*)(ob + 4) = (f32x4){o8[4], o8[5], o8[6], o8[7]};
            }
        }
    }
}

// ---------------------------------------------------------------------------
// MFMA attention. Block per (bp, head), 4 waves.  K frags hoisted (R7),
// Vt staging vectorized (R8).
// ---------------------------------------------------------------------------
__global__ __launch_bounds__(256) void attn_mfma(
    const unsigned short* __restrict__ qkv, unsigned short* __restrict__ o)
{
    __shared__ unsigned short Vt[64 * 256];
    __shared__ unsigned short Ps[4][16 * 256];
    int bp = blockIdx.x >> 3, h = blockIdx.x & 7;
    const unsigned short* base = qkv + (size_t)bp * 256 * 1536;
    int qo = h << 6, ko = 512 + (h << 6), vo = 1024 + (h << 6);
    int tid = threadIdx.x, w = tid >> 6, lane = tid & 63;
    int l15 = lane & 15, g = lane >> 4;

    {
        int d0 = (tid & 7) * 8;
        int sb = tid >> 3;                    // 32 rows per round
        #pragma unroll
        for (int r = 0; r < 8; ++r) {
            int s = sb + r * 32;
            short8 v = *(const short8*)(base + (size_t)s * 1536 + vo + d0);
            char* pbase = (char*)Vt + ((s & 7) << 1);
            int srow = s >> 3;
            #pragma unroll
            for (int j = 0; j < 8; ++j)
                *(unsigned short*)(pbase + (d0 + j) * 512 + ((srow ^ j) << 4)) =
                    (unsigned short)v[j];
        }
    }
    __syncthreads();

    short8 kb[16][2];
    #pragma unroll
    for (int ns = 0; ns < 16; ++ns)
        #pragma unroll
        for (int t = 0; t < 2; ++t)
            kb[ns][t] = *(const short8*)(base + (size_t)(ns * 16 + l15) * 1536 + ko + t * 32 + g * 8);

    unsigned short* P = Ps[w];

    for (int pass = 0; pass < 4; ++pass) {
        int q0 = pass * 64 + w * 16;
        short8 qa[2];
        #pragma unroll
        for (int t = 0; t < 2; ++t)
            qa[t] = *(const short8*)(base + (size_t)(q0 + l15) * 1536 + qo + t * 32 + g * 8);
        f32x4 S[16];
        #pragma unroll
        for (int ns = 0; ns < 16; ++ns) {
            f32x4 a = {0.f, 0.f, 0.f, 0.f};
            #pragma unroll
            for (int t = 0; t < 2; ++t)
                a = __builtin_amdgcn_mfma_f32_16x16x32_bf16(qa[t], kb[ns][t], a, 0, 0, 0);
            S[ns] = a;
        }
        float mx[4], sums[4], inv[4];
        #pragma unroll
        for (int r = 0; r < 4; ++r) {
            float m = -1e30f;
            #pragma unroll
            for (int ns = 0; ns < 16; ++ns) m = fmaxf(m, S[ns][r]);
            m *= 0.125f;
            #pragma unroll
            for (int off = 1; off < 16; off <<= 1) m = fmaxf(m, __shfl_xor(m, off));
            mx[r] = m;
            sums[r] = 0.f;
        }
        #pragma unroll
        for (int ns = 0; ns < 16; ++ns)
            #pragma unroll
            for (int r = 0; r < 4; ++r) {
                float p = __expf(S[ns][r] * 0.125f - mx[r]);
                sums[r] += p;
                S[ns][r] = p;
            }
        #pragma unroll
        for (int r = 0; r < 4; ++r) {
            float s2 = sums[r];
            #pragma unroll
            for (int off = 1; off < 16; off <<= 1) s2 += __shfl_xor(s2, off);
            inv[r] = 1.0f / s2;
        }
        #pragma unroll
        for (int ns = 0; ns < 16; ++ns)
            #pragma unroll
            for (int r = 0; r < 4; ++r) {
                int mq = g * 4 + r;
                int s = ns * 16 + l15;
                *(unsigned short*)((char*)P + mq * 512 + (((s >> 3) ^ (mq & 7)) << 4) + ((s & 7) << 1))
                    = f2bf(S[ns][r] * inv[r]);
            }
        f32x4 O[4];
        #pragma unroll
        for (int ds = 0; ds < 4; ++ds) O[ds] = (f32x4){0.f, 0.f, 0.f, 0.f};
        #pragma unroll
        for (int ks = 0; ks < 8; ++ks) {
            int c = (ks * 4 + g) ^ (l15 & 7);
            short8 pa = *(const short8*)((const char*)P + l15 * 512 + (c << 4));
            #pragma unroll
            for (int ds = 0; ds < 4; ++ds) {
                short8 vb = *(const short8*)((const char*)Vt + (ds * 16 + l15) * 512 + (c << 4));
                O[ds] = __builtin_amdgcn_mfma_f32_16x16x32_bf16(pa, vb, O[ds], 0, 0, 0);
            }
        }
        #pragma unroll
        for (int ds = 0; ds < 4; ++ds)
            #pragma unroll
            for (int r = 0; r < 4; ++r) {
                int mq = q0 + g * 4 + r;
                int d = ds * 16 + l15;
                o[((size_t)(bp * 256 + mq) << 9) + (h << 6) + d] = f2bf(O[ds][r]);
            }
    }
}

// ---------------------------------------------------------------------------
// Orchestration.  dtype decided host-side from in_sizes[1]; bf16 datasets
// use weights/params zero-copy.  GEMM routing: mlp1 -> gemm_256 (grid 512,
// 2 exact 1/CU rounds); qkv/proj/mlp2 -> gemm8.
// ---------------------------------------------------------------------------
extern "C" void kernel_launch(void* const* d_in, const int* in_sizes, int n_in,
                              void* d_out, int out_size, void* d_ws, size_t ws_size,
                              hipStream_t stream)
{
    const void* x      = d_in[0];
    const void* ln1_g  = d_in[1];
    const void* ln1_b  = d_in[2];
    const void* w_qkv  = d_in[3];
    const void* w_proj = d_in[4];
    const void* b_proj = d_in[5];
    const void* ln2_g  = d_in[6];
    const void* ln2_b  = d_in[7];
    const void* w1     = d_in[8];
    const void* b1     = d_in[9];
    const void* w2     = d_in[10];
    const void* b2     = d_in[11];
    const unsigned* dt = (const unsigned*)ln1_g;

    const int isbf = (in_sizes[1] == 512 * 2);   // ln1_g byte size

    const int M = 16384;
    char* ws = (char*)d_ws;
    unsigned short* wqkv_b  = (unsigned short*)(ws);
    unsigned short* wproj_b = (unsigned short*)(ws + 1572864);
    unsigned short* w1_b    = (unsigned short*)(ws + 2097152);
    unsigned short* w2_b    = (unsigned short*)(ws + 4194304);
    unsigned short* par     = (unsigned short*)(ws + 6291456);
    const size_t CAST_END = 6308096;

    const unsigned short* p_wqkv  = isbf ? (const unsigned short*)w_qkv  : wqkv_b;
    const unsigned short* p_wproj = isbf ? (const unsigned short*)w_proj : wproj_b;
    const unsigned short* p_w1    = isbf ? (const unsigned short*)w1     : w1_b;
    const unsigned short* p_w2    = isbf ? (const unsigned short*)w2     : w2_b;
    const unsigned short* p_g1    = isbf ? (const unsigned short*)ln1_g  : par + 0;
    const unsigned short* p_b1ln  = isbf ? (const unsigned short*)ln1_b  : par + 512;
    const unsigned short* p_bproj = isbf ? (const unsigned short*)b_proj : par + 1024;
    const unsigned short* p_g2    = isbf ? (const unsigned short*)ln2_g  : par + 1536;
    const unsigned short* p_b2ln  = isbf ? (const unsigned short*)ln2_b  : par + 2048;
    const unsigned short* p_b1    = isbf ? (const unsigned short*)b1     : par + 2560;
    const unsigned short* p_b2    = isbf ? (const unsigned short*)b2     : par + 4608;

    int NC = 64;
    const int cand[7] = {1, 2, 4, 8, 16, 32, 64};
    for (int i = 0; i < 7; ++i) {
        size_t need = CAST_END + (size_t)(M / cand[i]) * 10240;
        if (need <= ws_size) { NC = cand[i]; break; }
    }
    const int R = M / NC;          // multiple of 256

    char* cb = ws + CAST_END;
    unsigned short* h   = (unsigned short*)(cb);
    unsigned short* qkv = (unsigned short*)(cb + (size_t)R * 1024);
    unsigned short* o   = (unsigned short*)(cb + (size_t)R * 4096);
    unsigned short* x2  = (unsigned short*)(cb + (size_t)R * 5120);
    unsigned short* hid = (unsigned short*)(cb + (size_t)R * 6144);
    unsigned short* h2  = h;

    if (!isbf) {
        cast_all<<<775, 512, 0, stream>>>(w_qkv, w_proj, w1, w2,
                                          ln1_g, ln1_b, b_proj, ln2_g, ln2_b, b1, b2,
                                          wqkv_b, wproj_b, w1_b, w2_b, par, dt);
    }

    for (int c = 0; c < NC; ++c) {
        const size_t r0 = (size_t)c * R;
        const int NBY  = R / 128;      // 128-row tiles (gemm8)
        const int NBY2 = R / 256;      // 256-row tiles (gemm_256)

        ln_kernel<<<R / 4, 256, 0, stream>>>(x, r0, isbf ? 0 : 1, p_g1, p_b1ln, h);
        gemm8<<<(1536 / 128) * NBY, 256, 0, stream>>>(
            h, p_wqkv, nullptr, nullptr, 0, qkv, 0, NBY, 1536, 512, 0, isbf);
        attn_mfma<<<(R / 256) * 8, 256, 0, stream>>>(qkv, o);
        gemm8<<<(512 / 128) * NBY, 256, 0, stream>>>(
            o, p_wproj, p_bproj, x, r0, x2, 0, NBY, 512, 512, 1, isbf);
        ln_kernel<<<R / 4, 256, 0, stream>>>(x2, 0, 0, p_g2, p_b2ln, h2);
        gemm_256<<<(2048 / 256) * NBY2, 512, 0, stream>>>(
            h2, p_w1, p_b1, hid, NBY2, 2048, 512, 2);
        gemm8<<<(512 / 128) * NBY, 256, 0, stream>>>(
            hid, p_w2, p_b2, x2, 0, d_out, r0, NBY, 512, 2048, 3, isbf);
    }
}

// Round 10
// 304.144 us; speedup vs baseline: 1.0386x; 1.0386x over previous
//
#include <hip/hip_runtime.h>

typedef __attribute__((ext_vector_type(8))) short short8;
typedef __attribute__((ext_vector_type(4))) float f32x4;
typedef __attribute__((ext_vector_type(4))) unsigned short u16x4;
typedef __attribute__((ext_vector_type(2))) unsigned int u32x2;
typedef __attribute__((ext_vector_type(4))) unsigned int u32x4;

__device__ __forceinline__ float bf2f(unsigned short u) {
    return __uint_as_float(((unsigned)u) << 16);
}
__device__ __forceinline__ unsigned short f2bf(float f) {
    unsigned u = __float_as_uint(f);
    u += 0x7fffu + ((u >> 16) & 1u);   // round-to-nearest-even
    return (unsigned short)(u >> 16);
}
// HW packed f32->bf16 convert (RNE): lo16=cvt(a), hi16=cvt(b).
__device__ __forceinline__ unsigned pack2(float a, float b) {
    unsigned r;
    asm("v_cvt_pk_bf16_f32 %0, %1, %2" : "=v"(r) : "v"(a), "v"(b));
    return r;
}
__device__ __forceinline__ void load_lds16(const void* g, void* l) {
    __builtin_amdgcn_global_load_lds(
        (const __attribute__((address_space(1))) void*)g,
        (__attribute__((address_space(3))) void*)l, 16, 0, 0);
}
// device-side dtype probe (only used by cast_all, which runs fp32-only now)
__device__ __forceinline__ bool is_bf16(const unsigned* dt) {
    return *dt == 0x3F803F80u;
}
// gelu via exact identity 0.5*(1+tanh(u)) = sigmoid(2u); overflow-safe.
__device__ __forceinline__ float gelu_fast(float t) {
    float q = t * (1.5957691f + 0.07135482f * t * t);   // 2u
    float e = __expf(-q);
    return __fdividef(t, 1.0f + e);
}

// ---------------------------------------------------------------------------
// One-shot cast of all weights/params to bf16 in ws (fp32 datasets only).
// ---------------------------------------------------------------------------
__global__ __launch_bounds__(512) void cast_all(
    const void* s_wqkv, const void* s_wproj, const void* s_w1, const void* s_w2,
    const void* v0, const void* v1, const void* v2, const void* v3,
    const void* v4, const void* v5, const void* v6,
    unsigned short* d_wqkv, unsigned short* d_wproj, unsigned short* d_w1,
    unsigned short* d_w2, unsigned short* par, const unsigned* dt)
{
    bool isbf = is_bf16(dt);
    int b = blockIdx.x, tid = threadIdx.x;
    if (b < 768) {
        const void* src; unsigned short* dst; int off;
        if (b < 192)      { src = s_wqkv;  dst = d_wqkv;  off = b * 4096; }
        else if (b < 256) { src = s_wproj; dst = d_wproj; off = (b - 192) * 4096; }
        else if (b < 512) { src = s_w1;    dst = d_w1;    off = (b - 256) * 4096; }
        else              { src = s_w2;    dst = d_w2;    off = (b - 512) * 4096; }
        int i = off + tid * 8;
        if (isbf) {
            *(short8*)(dst + i) = *(const short8*)((const unsigned short*)src + i);
        } else {
            const float* s = (const float*)src + i;
            short8 o;
            #pragma unroll
            for (int j = 0; j < 8; ++j) o[j] = (short)f2bf(s[j]);
            *(short8*)(dst + i) = o;
        }
    } else {
        const void* srcs[7]  = {v0, v1, v2, v3, v4, v5, v6};
        const int   sizes[7] = {512, 512, 512, 512, 512, 2048, 512};
        const int   offs[7]  = {0, 512, 1024, 1536, 2048, 2560, 4608};
        int j = b - 768;
        const void* s = srcs[j];
        unsigned short* d = par + offs[j];
        for (int i = tid; i < sizes[j]; i += 512)
            d[i] = isbf ? ((const unsigned short*)s)[i] : f2bf(((const float*)s)[i]);
    }
}

// ---------------------------------------------------------------------------
// LayerNorm: one wave per row of 512, lane owns 8 contiguous elements.
// ---------------------------------------------------------------------------
__global__ __launch_bounds__(256) void ln_kernel(
    const void* __restrict__ xin, size_t row0, int isf32,
    const unsigned short* __restrict__ g, const unsigned short* __restrict__ b,
    unsigned short* __restrict__ y)
{
    int w = threadIdx.x >> 6, lane = threadIdx.x & 63;
    size_t lr = (size_t)blockIdx.x * 4 + w;
    size_t gr = row0 + lr;
    float v[8];
    if (isf32) {
        const float* xr = (const float*)xin + (gr << 9) + (lane << 3);
        #pragma unroll
        for (int j = 0; j < 8; ++j) v[j] = xr[j];
    } else {
        short8 raw = *(const short8*)((const unsigned short*)xin + (gr << 9) + (lane << 3));
        #pragma unroll
        for (int j = 0; j < 8; ++j) v[j] = bf2f((unsigned short)raw[j]);
    }
    float sum = 0.f, sq = 0.f;
    #pragma unroll
    for (int j = 0; j < 8; ++j) { sum += v[j]; sq += v[j] * v[j]; }
    #pragma unroll
    for (int off = 32; off > 0; off >>= 1) {
        sum += __shfl_xor(sum, off);
        sq  += __shfl_xor(sq, off);
    }
    float mu  = sum * (1.0f / 512.0f);
    float var = sq * (1.0f / 512.0f) - mu * mu;
    float rs  = rsqrtf(var + 1e-5f);
    short8 gr8 = *(const short8*)(g + (lane << 3));
    short8 br8 = *(const short8*)(b + (lane << 3));
    float o[8];
    #pragma unroll
    for (int j = 0; j < 8; ++j)
        o[j] = (v[j] - mu) * rs * bf2f((unsigned short)gr8[j]) + bf2f((unsigned short)br8[j]);
    u32x4 ov = {pack2(o[0], o[1]), pack2(o[2], o[3]),
                pack2(o[4], o[5]), pack2(o[6], o[7])};
    *(u32x4*)(y + (lr << 9) + (lane << 3)) = ov;
}

// ---------------------------------------------------------------------------
// gemm_big: BM=256, BN=128, BK=64, 256 thr / 4 waves, wave tile 128x64,
// acc[4][8], single 48KB LDS, 2-barrier K-loop, 2 blocks/CU.  Used for
// mlp1 only (grid 1024 = 2 exact 2/CU rounds).
// SCHEDULE NOTE (R1/R2/R9 closed): phase-pipelined variants (counted vmcnt,
// dbuf, setprio, 256^2 quadrant phases) all LOSE to this simple 2-barrier
// loop on shallow-K shapes (8 K-tiles): 73/75/65us vs 57.6-60.5us.  The
// pipeline's cover never amortizes prologue/epilogue + fill rounds at
// 1 block/CU.  Do not retry without K >= ~32 tiles.
// Epilogue: LDS-transpose (R6 direct-store regressed on write coalescing).
// ---------------------------------------------------------------------------
__global__ __launch_bounds__(256, 2) void gemm_big(
    const unsigned short* __restrict__ A, const unsigned short* __restrict__ W,
    const unsigned short* __restrict__ bias,
    unsigned short* __restrict__ out,
    int NBY, int N, int K, int mode)
{
    __shared__ char lds[49152];

    int tid = threadIdx.x;
    int w = tid >> 6, lane = tid & 63;
    int l15 = lane & 15, g = lane >> 4;

    int L = blockIdx.x;
    int bx, by;
    if ((NBY & 7) == 0) {
        int nby8 = NBY >> 3;
        int xcd = L & 7, i = L >> 3;
        by = xcd * nby8 + (i % nby8);
        bx = i / nby8;
    } else {
        by = L % NBY;
        bx = L / NBY;
    }
    int m0 = by << 8, n0 = bx << 7;
    int wm = (w >> 1) << 7;                  // 0,128
    int wn = (w & 1) << 6;                   // 0,64

    int srow = tid >> 3;
    int u = (tid & 7) ^ (srow & 7);
    const unsigned short* gA[8];
    const unsigned short* gB[4];
    #pragma unroll
    for (int j = 0; j < 8; ++j)
        gA[j] = A + (size_t)(m0 + j * 32 + srow) * K + u * 8;
    #pragma unroll
    for (int j = 0; j < 4; ++j)
        gB[j] = W + (size_t)(n0 + j * 32 + srow) * K + u * 8;
    int lslot = tid * 16;
    int swz = l15 & 7;

    f32x4 acc[4][8];
    #pragma unroll
    for (int i = 0; i < 4; ++i)
        #pragma unroll
        for (int j = 0; j < 8; ++j) acc[i][j] = (f32x4){0.f, 0.f, 0.f, 0.f};

    for (int k = 0; k < K; k += 64) {
        if (k > 0) __syncthreads();
        #pragma unroll
        for (int j = 0; j < 8; ++j)
            load_lds16(gA[j] + k, &lds[j * 4096 + lslot]);
        #pragma unroll
        for (int j = 0; j < 4; ++j)
            load_lds16(gB[j] + k, &lds[32768 + j * 4096 + lslot]);
        __syncthreads();
        const char* bAct = lds;
        const char* bW = lds + 32768;
        #pragma unroll
        for (int s = 0; s < 2; ++s) {
            int cs = ((s * 4 + g) ^ swz) << 4;
            short8 wf[4];
            #pragma unroll
            for (int i = 0; i < 4; ++i)
                wf[i] = *(const short8*)(bW + (wn + i * 16 + l15) * 128 + cs);
            #pragma unroll
            for (int jg = 0; jg < 8; jg += 4) {
                short8 af[4];
                #pragma unroll
                for (int j = 0; j < 4; ++j)
                    af[j] = *(const short8*)(bAct + (wm + (jg + j) * 16 + l15) * 128 + cs);
                #pragma unroll
                for (int i = 0; i < 4; ++i)
                    #pragma unroll
                    for (int j = 0; j < 4; ++j)
                        acc[i][jg + j] = __builtin_amdgcn_mfma_f32_16x16x32_bf16(
                            wf[i], af[j], acc[i][jg + j], 0, 0, 0);
            }
        }
    }
    __syncthreads();

    if (mode == 2) {
        #pragma unroll
        for (int i = 0; i < 4; ++i) {
            u16x4 bb = *(const u16x4*)(bias + n0 + wn + i * 16 + g * 4);
            #pragma unroll
            for (int j = 0; j < 8; ++j)
                #pragma unroll
                for (int r = 0; r < 4; ++r)
                    acc[i][j][r] = gelu_fast(acc[i][j][r] + bf2f(bb[r]));
        }
    }

    // two-half transpose + readout (rows local 0..127 per half)
    #pragma unroll
    for (int hh = 0; hh < 2; ++hh) {
        if ((w >> 1) == hh) {
            #pragma unroll
            for (int j = 0; j < 8; ++j) {
                int mloc = j * 16 + l15;
                char* rowp = lds + mloc * 256;
                int sw = mloc & 30;
                #pragma unroll
                for (int i = 0; i < 4; ++i) {
                    int cq = (wn + i * 16 + g * 4) >> 2;
                    u32x2 pk = {pack2(acc[i][j][0], acc[i][j][1]),
                                pack2(acc[i][j][2], acc[i][j][3])};
                    *(u32x2*)(rowp + ((cq ^ sw) << 3)) = pk;
                }
            }
        }
        __syncthreads();
        int rL = tid >> 4, lc = tid & 15;
        int colg = n0 + lc * 8;
        #pragma unroll
        for (int ps = 0; ps < 8; ++ps) {
            int row = ps * 16 + rL;
            int rowL = m0 + hh * 128 + row;
            int c16 = lc ^ ((row >> 1) & 15);
            short8 vv = *(const short8*)(lds + row * 256 + (c16 << 4));
            *(short8*)(out + (size_t)rowL * N + colg) = vv;
        }
        if (hh == 0) __syncthreads();
    }
}

// ---------------------------------------------------------------------------
// gemm8: BM=BN=128, BK=64, 256 thr, single 32KB buffer, 2-barrier loop,
// ~3 blocks/CU.  Used for qkv (mode 0), proj (mode 1), mlp2 (mode 3).
// ---------------------------------------------------------------------------
__global__ __launch_bounds__(256) void gemm8(
    const unsigned short* __restrict__ A, const unsigned short* __restrict__ W,
    const unsigned short* __restrict__ bias,
    const void* __restrict__ resid, size_t rrow0,
    void* __restrict__ out, size_t orow0,
    int NBY, int N, int K, int mode, int inbf)
{
    constexpr int BN = 128;
    __shared__ char lds[32768];

    int tid = threadIdx.x;
    int w = tid >> 6, lane = tid & 63;
    int l15 = lane & 15, g = lane >> 4;

    int L = blockIdx.x;
    int bx, by;
    if ((NBY & 7) == 0) {
        int nby8 = NBY >> 3;
        int xcd = L & 7, i = L >> 3;
        by = xcd * nby8 + (i % nby8);
        bx = i / nby8;
    } else {
        by = L % NBY;
        bx = L / NBY;
    }
    int m0 = by << 7, n0 = bx << 7;
    int wm = (w >> 1) << 6;
    int wn = (w & 1) << 6;

    int srow_t = tid >> 3;
    int u_t = (tid & 7) ^ (srow_t & 7);
    const unsigned short* gA[4];
    const unsigned short* gB[4];
    #pragma unroll
    for (int j = 0; j < 4; ++j) {
        gA[j] = A + (size_t)(m0 + j * 32 + srow_t) * K + u_t * 8;
        gB[j] = W + (size_t)(n0 + j * 32 + srow_t) * K + u_t * 8;
    }
    int lslot = tid * 16;
    int swz = l15 & 7;

    f32x4 acc[4][4];
    #pragma unroll
    for (int i = 0; i < 4; ++i)
        #pragma unroll
        for (int j = 0; j < 4; ++j) acc[i][j] = (f32x4){0.f, 0.f, 0.f, 0.f};

    for (int k = 0; k < K; k += 64) {
        if (k > 0) __syncthreads();
        #pragma unroll
        for (int j = 0; j < 4; ++j) {
            load_lds16(gA[j] + k, &lds[j * 4096 + lslot]);
            load_lds16(gB[j] + k, &lds[16384 + j * 4096 + lslot]);
        }
        __syncthreads();
        const char* bAct = lds;
        const char* bW = bAct + 16384;
        #pragma unroll
        for (int s = 0; s < 2; ++s) {
            int cs = ((s * 4 + g) ^ swz) << 4;
            short8 wf[4], af[4];
            #pragma unroll
            for (int i = 0; i < 4; ++i)
                wf[i] = *(const short8*)(bW + (wn + i * 16 + l15) * 128 + cs);
            #pragma unroll
            for (int j = 0; j < 4; ++j)
                af[j] = *(const short8*)(bAct + (wm + j * 16 + l15) * 128 + cs);
            #pragma unroll
            for (int i = 0; i < 4; ++i)
                #pragma unroll
                for (int j = 0; j < 4; ++j)
                    acc[i][j] = __builtin_amdgcn_mfma_f32_16x16x32_bf16(wf[i], af[j], acc[i][j], 0, 0, 0);
        }
    }
    __syncthreads();

    char* tb = (char*)lds;
    #pragma unroll
    for (int j = 0; j < 4; ++j) {
        int mloc = wm + j * 16 + l15;
        char* rowp = tb + mloc * (BN * 2);
        int sw = mloc & (BN / 4 - 2);
        #pragma unroll
        for (int i = 0; i < 4; ++i) {
            int cq = (wn + i * 16 + g * 4) >> 2;
            u32x2 pk = {pack2(acc[i][j][0], acc[i][j][1]),
                        pack2(acc[i][j][2], acc[i][j][3])};
            *(u32x2*)(rowp + ((cq ^ sw) << 3)) = pk;
        }
    }
    __syncthreads();

    int rL = tid >> 4;
    int lc = tid & 15;
    int colg = n0 + lc * 8;
    float bv[8];
    if (mode != 0) {
        short8 bb = *(const short8*)(bias + colg);
        #pragma unroll
        for (int t = 0; t < 8; ++t) bv[t] = bf2f((unsigned short)bb[t]);
    }

    #pragma unroll
    for (int ps = 0; ps < 8; ++ps) {
        int row = ps * 16 + rL;
        int rowL = m0 + row;
        int c16 = lc ^ ((row >> 1) & 15);
        short8 vv = *(const short8*)(tb + row * (BN * 2) + (c16 << 4));

        if (mode == 0) {
            *(short8*)((unsigned short*)out + (size_t)rowL * N + colg) = vv;
        } else if (mode == 1) {
            size_t rbase = (rrow0 + rowL) * (size_t)N + colg;
            float o8[8];
            if (inbf) {
                short8 rr = *(const short8*)((const unsigned short*)resid + rbase);
                #pragma unroll
                for (int t = 0; t < 8; ++t)
                    o8[t] = bf2f((unsigned short)rr[t]) + bf2f((unsigned short)vv[t]) + bv[t];
            } else {
                f32x4 r0 = *(const f32x4*)((const float*)resid + rbase);
                f32x4 r1 = *(const f32x4*)((const float*)resid + rbase + 4);
                #pragma unroll
                for (int t = 0; t < 4; ++t) {
                    o8[t]     = r0[t] + bf2f((unsigned short)vv[t]) + bv[t];
                    o8[t + 4] = r1[t] + bf2f((unsigned short)vv[t + 4]) + bv[t + 4];
                }
            }
            u32x4 ov = {pack2(o8[0], o8[1]), pack2(o8[2], o8[3]),
                        pack2(o8[4], o8[5]), pack2(o8[6], o8[7])};
            *(u32x4*)((unsigned short*)out + (size_t)rowL * N + colg) = ov;
        } else {
            size_t rbase = (size_t)rowL * N + colg;
            short8 rr = *(const short8*)((const unsigned short*)resid + rbase);
            float o8[8];
            #pragma unroll
            for (int t = 0; t < 8; ++t)
                o8[t] = bf2f((unsigned short)rr[t]) + bf2f((unsigned short)vv[t]) + bv[t];
            size_t obase = (orow0 + rowL) * (size_t)N + colg;
            if (inbf) {
                u32x4 ov = {pack2(o8[0], o8[1]), pack2(o8[2], o8[3]),
                            pack2(o8[4], o8[5]), pack2(o8[6], o8[7])};
                *(u32x4*)((unsigned short*)out + obase) = ov;
            } else {
                float* ob = (float*)out + obase;
                *(f32x4*)ob       = (f32x4){o8[0], o8[1], o8[2], o8[3]};
                *(f32x4*)(ob + 4) = (f32x4){o8[4], o8[5], o8[6], o8[7]};
            }
        }
    }
}

// ---------------------------------------------------------------------------
// MFMA attention. Block per (bp, head), 4 waves.  K frags hoisted (R7),
// Vt staging vectorized (R8).
// CHANGE (R10): all f2bf converts in P-write and O-store replaced with
// v_cvt_pk_bf16_f32 pairs (same lever as R5's gemm_big epilogue, VALUBusy
// 50->41).  Stores stay b16 (addresses scatter across LDS/global rows);
// only the conversion is packed: 64 f2bf (~5 VALU ea) -> 32 cvt_pk + 32 shr
// per pass in P-write, 16 f2bf -> 8 cvt_pk + 8 shr in O-store.
// ---------------------------------------------------------------------------
__global__ __launch_bounds__(256) void attn_mfma(
    const unsigned short* __restrict__ qkv, unsigned short* __restrict__ o)
{
    __shared__ unsigned short Vt[64 * 256];
    __shared__ unsigned short Ps[4][16 * 256];
    int bp = blockIdx.x >> 3, h = blockIdx.x & 7;
    const unsigned short* base = qkv + (size_t)bp * 256 * 1536;
    int qo = h << 6, ko = 512 + (h << 6), vo = 1024 + (h << 6);
    int tid = threadIdx.x, w = tid >> 6, lane = tid & 63;
    int l15 = lane & 15, g = lane >> 4;

    {
        int d0 = (tid & 7) * 8;
        int sb = tid >> 3;                    // 32 rows per round
        #pragma unroll
        for (int r = 0; r < 8; ++r) {
            int s = sb + r * 32;
            short8 v = *(const short8*)(base + (size_t)s * 1536 + vo + d0);
            char* pbase = (char*)Vt + ((s & 7) << 1);
            int srow = s >> 3;
            #pragma unroll
            for (int j = 0; j < 8; ++j)
                *(unsigned short*)(pbase + (d0 + j) * 512 + ((srow ^ j) << 4)) =
                    (unsigned short)v[j];
        }
    }
    __syncthreads();

    short8 kb[16][2];
    #pragma unroll
    for (int ns = 0; ns < 16; ++ns)
        #pragma unroll
        for (int t = 0; t < 2; ++t)
            kb[ns][t] = *(const short8*)(base + (size_t)(ns * 16 + l15) * 1536 + ko + t * 32 + g * 8);

    unsigned short* P = Ps[w];

    for (int pass = 0; pass < 4; ++pass) {
        int q0 = pass * 64 + w * 16;
        short8 qa[2];
        #pragma unroll
        for (int t = 0; t < 2; ++t)
            qa[t] = *(const short8*)(base + (size_t)(q0 + l15) * 1536 + qo + t * 32 + g * 8);
        f32x4 S[16];
        #pragma unroll
        for (int ns = 0; ns < 16; ++ns) {
            f32x4 a = {0.f, 0.f, 0.f, 0.f};
            #pragma unroll
            for (int t = 0; t < 2; ++t)
                a = __builtin_amdgcn_mfma_f32_16x16x32_bf16(qa[t], kb[ns][t], a, 0, 0, 0);
            S[ns] = a;
        }
        float mx[4], sums[4], inv[4];
        #pragma unroll
        for (int r = 0; r < 4; ++r) {
            float m = -1e30f;
            #pragma unroll
            for (int ns = 0; ns < 16; ++ns) m = fmaxf(m, S[ns][r]);
            m *= 0.125f;
            #pragma unroll
            for (int off = 1; off < 16; off <<= 1) m = fmaxf(m, __shfl_xor(m, off));
            mx[r] = m;
            sums[r] = 0.f;
        }
        #pragma unroll
        for (int ns = 0; ns < 16; ++ns)
            #pragma unroll
            for (int r = 0; r < 4; ++r) {
                float p = __expf(S[ns][r] * 0.125f - mx[r]);
                sums[r] += p;
                S[ns][r] = p;
            }
        #pragma unroll
        for (int r = 0; r < 4; ++r) {
            float s2 = sums[r];
            #pragma unroll
            for (int off = 1; off < 16; off <<= 1) s2 += __shfl_xor(s2, off);
            inv[r] = 1.0f / s2;
        }
        // P-write: cvt_pk pairs (r, r+1); per pair one u32, two b16 stores
        #pragma unroll
        for (int ns = 0; ns < 16; ++ns) {
            int s = ns * 16 + l15;
            int sb4 = ((s & 7) << 1);
            int sh = s >> 3;
            #pragma unroll
            for (int rp = 0; rp < 4; rp += 2) {
                unsigned pk = pack2(S[ns][rp] * inv[rp], S[ns][rp + 1] * inv[rp + 1]);
                int mq0 = g * 4 + rp;
                int mq1 = mq0 + 1;
                *(unsigned short*)((char*)P + mq0 * 512 + ((sh ^ (mq0 & 7)) << 4) + sb4)
                    = (unsigned short)pk;
                *(unsigned short*)((char*)P + mq1 * 512 + ((sh ^ (mq1 & 7)) << 4) + sb4)
                    = (unsigned short)(pk >> 16);
            }
        }
        f32x4 O[4];
        #pragma unroll
        for (int ds = 0; ds < 4; ++ds) O[ds] = (f32x4){0.f, 0.f, 0.f, 0.f};
        #pragma unroll
        for (int ks = 0; ks < 8; ++ks) {
            int c = (ks * 4 + g) ^ (l15 & 7);
            short8 pa = *(const short8*)((const char*)P + l15 * 512 + (c << 4));
            #pragma unroll
            for (int ds = 0; ds < 4; ++ds) {
                short8 vb = *(const short8*)((const char*)Vt + (ds * 16 + l15) * 512 + (c << 4));
                O[ds] = __builtin_amdgcn_mfma_f32_16x16x32_bf16(pa, vb, O[ds], 0, 0, 0);
            }
        }
        // O-store: cvt_pk pairs (r, r+1) -> two b16 stores to rows mq, mq+1
        #pragma unroll
        for (int ds = 0; ds < 4; ++ds) {
            int d = ds * 16 + l15;
            #pragma unroll
            for (int rp = 0; rp < 4; rp += 2) {
                unsigned pk = pack2(O[ds][rp], O[ds][rp + 1]);
                int mq = q0 + g * 4 + rp;
                o[((size_t)(bp * 256 + mq) << 9) + (h << 6) + d] = (unsigned short)pk;
                o[((size_t)(bp * 256 + mq + 1) << 9) + (h << 6) + d] = (unsigned short)(pk >> 16);
            }
        }
    }
}

// ---------------------------------------------------------------------------
// Orchestration.  dtype decided host-side from in_sizes[1]; bf16 datasets
// use weights/params zero-copy.  GEMM routing: mlp1 -> gemm_big (grid 1024
// = 2 exact 2/CU rounds); qkv/proj/mlp2 -> gemm8 (qkv: 1536 = 2 exact 3/CU
// rounds; gemm_big's 768 grid had a 1.5-round tail costing ~6us).
// ---------------------------------------------------------------------------
extern "C" void kernel_launch(void* const* d_in, const int* in_sizes, int n_in,
                              void* d_out, int out_size, void* d_ws, size_t ws_size,
                              hipStream_t stream)
{
    const void* x      = d_in[0];
    const void* ln1_g  = d_in[1];
    const void* ln1_b  = d_in[2];
    const void* w_qkv  = d_in[3];
    const void* w_proj = d_in[4];
    const void* b_proj = d_in[5];
    const void* ln2_g  = d_in[6];
    const void* ln2_b  = d_in[7];
    const void* w1     = d_in[8];
    const void* b1     = d_in[9];
    const void* w2     = d_in[10];
    const void* b2     = d_in[11];
    const unsigned* dt = (const unsigned*)ln1_g;

    const int isbf = (in_sizes[1] == 512 * 2);   // ln1_g byte size

    const int M = 16384;
    char* ws = (char*)d_ws;
    unsigned short* wqkv_b  = (unsigned short*)(ws);
    unsigned short* wproj_b = (unsigned short*)(ws + 1572864);
    unsigned short* w1_b    = (unsigned short*)(ws + 2097152);
    unsigned short* w2_b    = (unsigned short*)(ws + 4194304);
    unsigned short* par     = (unsigned short*)(ws + 6291456);
    const size_t CAST_END = 6308096;

    const unsigned short* p_wqkv  = isbf ? (const unsigned short*)w_qkv  : wqkv_b;
    const unsigned short* p_wproj = isbf ? (const unsigned short*)w_proj : wproj_b;
    const unsigned short* p_w1    = isbf ? (const unsigned short*)w1     : w1_b;
    const unsigned short* p_w2    = isbf ? (const unsigned short*)w2     : w2_b;
    const unsigned short* p_g1    = isbf ? (const unsigned short*)ln1_g  : par + 0;
    const unsigned short* p_b1ln  = isbf ? (const unsigned short*)ln1_b  : par + 512;
    const unsigned short* p_bproj = isbf ? (const unsigned short*)b_proj : par + 1024;
    const unsigned short* p_g2    = isbf ? (const unsigned short*)ln2_g  : par + 1536;
    const unsigned short* p_b2ln  = isbf ? (const unsigned short*)ln2_b  : par + 2048;
    const unsigned short* p_b1    = isbf ? (const unsigned short*)b1     : par + 2560;
    const unsigned short* p_b2    = isbf ? (const unsigned short*)b2     : par + 4608;

    int NC = 64;
    const int cand[7] = {1, 2, 4, 8, 16, 32, 64};
    for (int i = 0; i < 7; ++i) {
        size_t need = CAST_END + (size_t)(M / cand[i]) * 10240;
        if (need <= ws_size) { NC = cand[i]; break; }
    }
    const int R = M / NC;          // multiple of 256

    char* cb = ws + CAST_END;
    unsigned short* h   = (unsigned short*)(cb);
    unsigned short* qkv = (unsigned short*)(cb + (size_t)R * 1024);
    unsigned short* o   = (unsigned short*)(cb + (size_t)R * 4096);
    unsigned short* x2  = (unsigned short*)(cb + (size_t)R * 5120);
    unsigned short* hid = (unsigned short*)(cb + (size_t)R * 6144);
    unsigned short* h2  = h;

    if (!isbf) {
        cast_all<<<775, 512, 0, stream>>>(w_qkv, w_proj, w1, w2,
                                          ln1_g, ln1_b, b_proj, ln2_g, ln2_b, b1, b2,
                                          wqkv_b, wproj_b, w1_b, w2_b, par, dt);
    }

    for (int c = 0; c < NC; ++c) {
        const size_t r0 = (size_t)c * R;
        const int NBY  = R / 128;      // 128-row tiles (gemm8)
        const int NBY2 = R / 256;      // 256-row tiles (gemm_big)

        ln_kernel<<<R / 4, 256, 0, stream>>>(x, r0, isbf ? 0 : 1, p_g1, p_b1ln, h);
        gemm8<<<(1536 / 128) * NBY, 256, 0, stream>>>(
            h, p_wqkv, nullptr, nullptr, 0, qkv, 0, NBY, 1536, 512, 0, isbf);
        attn_mfma<<<(R / 256) * 8, 256, 0, stream>>>(qkv, o);
        gemm8<<<(512 / 128) * NBY, 256, 0, stream>>>(
            o, p_wproj, p_bproj, x, r0, x2, 0, NBY, 512, 512, 1, isbf);
        ln_kernel<<<R / 4, 256, 0, stream>>>(x2, 0, 0, p_g2, p_b2ln, h2);
        gemm_big<<<(2048 / 128) * NBY2, 256, 0, stream>>>(
            h2, p_w1, p_b1, hid, NBY2, 2048, 512, 2);
        gemm8<<<(512 / 128) * NBY, 256, 0, stream>>>(
            hid, p_w2, p_b2, x2, 0, d_out, r0, NBY, 512, 2048, 3, isbf);
    }
}